// Round 2
// baseline (1011.254 us; speedup 1.0000x reference)
//
#include <hip/hip_runtime.h>

#define NB 4096
#define NSEQ 64
#define CDIM 96
#define NH 3

typedef __attribute__((ext_vector_type(8))) short bf16x8;
typedef __attribute__((ext_vector_type(4))) float f32x4;
typedef unsigned short u16;

#define MFMA16 __builtin_amdgcn_mfma_f32_16x16x32_bf16
#define LOG2E 1.4426950408889634f

__device__ __forceinline__ unsigned pkbf(float a, float b) {
  unsigned r;
  asm("v_cvt_pk_bf16_f32 %0, %1, %2" : "=v"(r) : "v"(a), "v"(b));
  return r;
}

// ---------------- bias precompute in MFMA D-fragment layout, pre-scaled by log2(e):
// biasF[(t*3+h)*16 + fr*4+fc][lane] = float4 over r, value = log2e * tbl_t[rel[n][m], h]
// with m = 16*fr + 4*(lane>>4) + r (D row), n = 16*fc + (lane&15) (D col).
__global__ __launch_bounds__(256) void bias_pre_kernel(
    const float* __restrict__ tcv, const float* __restrict__ tsv,
    const float* __restrict__ tch, const float* __restrict__ tsh,
    const int* __restrict__ rel, float* __restrict__ biasF) {
  int idx = blockIdx.x * 256 + threadIdx.x;
  if (idx >= 4 * 3 * 16 * 64) return;
  int t = idx / (3 * 16 * 64);
  int r0 = idx % (3 * 16 * 64);
  int h = r0 / (16 * 64);
  int r1 = r0 % (16 * 64);
  int frag = r1 >> 6;
  int lane = r1 & 63;
  int fr = frag >> 2, fc = frag & 3;
  int g = lane >> 4, q = lane & 15;
  int n = 16 * fc + q;
  int m0 = 16 * fr + 4 * g;
  const float* tbl = (t == 0) ? tcv : (t == 1) ? tsv : (t == 2) ? tch : tsh;
  float4 v;
  v.x = LOG2E * tbl[rel[n * 64 + m0 + 0] * NH + h];
  v.y = LOG2E * tbl[rel[n * 64 + m0 + 1] * NH + h];
  v.z = LOG2E * tbl[rel[n * 64 + m0 + 2] * NH + h];
  v.w = LOG2E * tbl[rel[n * 64 + m0 + 3] * NH + h];
  ((float4*)biasF)[idx] = v;
}

// ---------------- weight fp32 -> bf16 (RNE)
// dst (u16): Ws[0..36864) We[36864..73728) Wpv[73728..92160) Wph[92160..110592)
__global__ __launch_bounds__(256) void wcvt_kernel(
    const float* __restrict__ Ws, const float* __restrict__ We,
    const float* __restrict__ Wpv, const float* __restrict__ Wph,
    u16* __restrict__ dst) {
  int i = blockIdx.x * 256 + threadIdx.x;
  if (i >= 110592) return;
  float v;
  if (i < 36864) v = Ws[i];
  else if (i < 73728) v = We[i - 36864];
  else if (i < 92160) v = Wpv[i - 73728];
  else v = Wph[i - 92160];
  unsigned u = __builtin_bit_cast(unsigned, v);
  u += 0x7FFFu + ((u >> 16) & 1u);
  dst[i] = (u16)(u >> 16);
}

// ---------------- main fused kernel: one block per window, wave = attn type
// w0: cv (q=qsv(S), K=ks(S), V=vs(S), sc)   w1: sv (qev(E), ke, ve, 1)
// w2: ch (qeh(E), ke, ve, sc)               w3: sh (qsh(S), ks, vs, sc^2)
// Frag conventions (gfx950 16x16x32):
//   A: row=lane&15, k=8*(lane>>4)+j ; B: col=lane&15, k=8*(lane>>4)+j
//   D: col=lane&15, row=4*(lane>>4)+r
// Phase 1 computes q,K as W*X^T (d-quads per lane -> b64 stores), V as X*W^T
// (m-quads -> b64 stores into swizzled V^T).
__global__ __launch_bounds__(256, 3) void rwa_kernel(
    const float* __restrict__ Xin, const float* __restrict__ Xst,
    const float* __restrict__ bs, const float* __restrict__ be,
    const float* __restrict__ bpv, const float* __restrict__ bph,
    const float* __restrict__ biasF, const u16* __restrict__ wbf,
    float* __restrict__ out) {
  const int b = blockIdx.x;
  const int t = threadIdx.x;
  const int wu = __builtin_amdgcn_readfirstlane(t >> 6);
  const int lane = t & 63;
  const int g = lane >> 4;
  const int q = lane & 15;

  // LDS map (u16 units), 25600 u16 = 51200 B -> 3 blocks/CU:
  // KS[64][40]=0  KE=2560  VSt swz[32][64]=5120  VEt=7168
  // perW[w]=9216+w*4096: Q[64][40] / P swz[64][64] / O[64][40] (overlaid)
  __shared__ __align__(16) u16 lds[25600];

  const int KS_u = 0, KE_u = 2560, VST_u = 5120, VET_u = 7168;
  const int PW_u = 9216 + wu * 4096;

  const float SC = 0.17677669529663687f;  // 32^-0.5
  const bool isS = (wu == 0 || wu == 3);
  const float* X = isS ? Xst : Xin;
  const u16* Wt = isS ? wbf : (wbf + 36864);
  const float* bt = isS ? bs : be;
  const int qf = (wu < 2) ? 2 : 3;
  const int sf = (wu < 2) ? 0 : 1;
  const int kb_u = (wu == 1 || wu == 2) ? KE_u : KS_u;
  const int vb_u = (wu == 1 || wu == 2) ? VET_u : VST_u;
  const int stage_u = (wu == 0) ? KS_u : (wu == 1) ? KE_u : (wu == 2) ? VET_u : VST_u;
  // q staged pre-scaled by sc*log2e; bias table pre-scaled by log2e -> raw v_exp
  const float scl = ((wu == 0 || wu == 2) ? SC : ((wu == 1) ? 1.0f : SC * SC)) * LOG2E;

  const u16* WpvB = wbf + 73728;
  const u16* WphB = wbf + 92160;

  // ---- X fragments (held across heads): serve as A (row=n) or B (col=n)
  bf16x8 xa[4][3];
#pragma unroll
  for (int fa = 0; fa < 4; fa++) {
    const float* xrow = X + ((size_t)b * NSEQ + 16 * fa + q) * CDIM;
#pragma unroll
    for (int kc = 0; kc < 3; kc++) {
      float4 lo = *(const float4*)(xrow + 32 * kc + 8 * g);
      float4 hi = *(const float4*)(xrow + 32 * kc + 8 * g + 4);
      union { bf16x8 v; unsigned u[4]; } tmp;
      tmp.u[0] = pkbf(lo.x, lo.y);
      tmp.u[1] = pkbf(lo.z, lo.w);
      tmp.u[2] = pkbf(hi.x, hi.y);
      tmp.u[3] = pkbf(hi.z, hi.w);
      xa[fa][kc] = tmp.v;
    }
  }

  // ---- final-projection accumulators: rows n=16*wu+4g+r, cols c=16*fc+q
  f32x4 accO[6], accS[6];
#pragma unroll
  for (int i = 0; i < 6; i++) {
    accO[i] = (f32x4){0.f, 0.f, 0.f, 0.f};
    accS[i] = (f32x4){0.f, 0.f, 0.f, 0.f};
  }

#pragma unroll 1
  for (int h = 0; h < NH; h++) {
    const int qbase = qf * CDIM + h * 32;
    const int sbase = sf * CDIM + h * 32;

    // ================= phase 1: projections
    if (wu < 2) {
      // q and K, swapped orientation: D[d][n], lane holds d=16cb+4g+r, n=16nb+q
      f32x4 pq[2][4], pk2[2][4];
#pragma unroll
      for (int cb = 0; cb < 2; cb++)
#pragma unroll
        for (int nb = 0; nb < 4; nb++) {
          pq[cb][nb] = (f32x4){0.f, 0.f, 0.f, 0.f};
          pk2[cb][nb] = (f32x4){0.f, 0.f, 0.f, 0.f};
        }
#pragma unroll
      for (int kc = 0; kc < 3; kc++) {
        bf16x8 wq[2], wk[2];
#pragma unroll
        for (int cb = 0; cb < 2; cb++) {
          wq[cb] = *(const bf16x8*)&Wt[(size_t)(qbase + 16 * cb + q) * CDIM + 32 * kc + 8 * g];
          wk[cb] = *(const bf16x8*)&Wt[(size_t)(sbase + 16 * cb + q) * CDIM + 32 * kc + 8 * g];
        }
#pragma unroll
        for (int cb = 0; cb < 2; cb++)
#pragma unroll
          for (int nb = 0; nb < 4; nb++) {
            pq[cb][nb] = MFMA16(wq[cb], xa[nb][kc], pq[cb][nb], 0, 0, 0);
            pk2[cb][nb] = MFMA16(wk[cb], xa[nb][kc], pk2[cb][nb], 0, 0, 0);
          }
      }
#pragma unroll
      for (int cb = 0; cb < 2; cb++) {
        float4 bq = *(const float4*)&bt[qbase + 16 * cb + 4 * g];
        float4 bk = *(const float4*)&bt[sbase + 16 * cb + 4 * g];
#pragma unroll
        for (int nb = 0; nb < 4; nb++) {
          int n = 16 * nb + q;
          f32x4 v = pq[cb][nb];
          uint2 w2;
          w2.x = pkbf((v[0] + bq.x) * scl, (v[1] + bq.y) * scl);
          w2.y = pkbf((v[2] + bq.z) * scl, (v[3] + bq.w) * scl);
          *(uint2*)&lds[PW_u + n * 40 + 16 * cb + 4 * g] = w2;
          f32x4 u = pk2[cb][nb];
          uint2 k2;
          k2.x = pkbf(u[0] + bk.x, u[1] + bk.y);
          k2.y = pkbf(u[2] + bk.z, u[3] + bk.w);
          *(uint2*)&lds[stage_u + n * 40 + 16 * cb + 4 * g] = k2;
        }
      }
    } else {
      // q swapped; V original orientation: D[n][ch], lane holds n=16fa+4g+r, ch=16fc+q
      f32x4 pq[2][4], pv[4][2];
#pragma unroll
      for (int cb = 0; cb < 2; cb++)
#pragma unroll
        for (int nb = 0; nb < 4; nb++) pq[cb][nb] = (f32x4){0.f, 0.f, 0.f, 0.f};
#pragma unroll
      for (int fa = 0; fa < 4; fa++)
#pragma unroll
        for (int fc = 0; fc < 2; fc++) pv[fa][fc] = (f32x4){0.f, 0.f, 0.f, 0.f};
#pragma unroll
      for (int kc = 0; kc < 3; kc++) {
        bf16x8 wq[2], wv[2];
#pragma unroll
        for (int cb = 0; cb < 2; cb++)
          wq[cb] = *(const bf16x8*)&Wt[(size_t)(qbase + 16 * cb + q) * CDIM + 32 * kc + 8 * g];
#pragma unroll
        for (int fc = 0; fc < 2; fc++)
          wv[fc] = *(const bf16x8*)&Wt[(size_t)(sbase + 16 * fc + q) * CDIM + 32 * kc + 8 * g];
#pragma unroll
        for (int cb = 0; cb < 2; cb++)
#pragma unroll
          for (int nb = 0; nb < 4; nb++)
            pq[cb][nb] = MFMA16(wq[cb], xa[nb][kc], pq[cb][nb], 0, 0, 0);
#pragma unroll
        for (int fa = 0; fa < 4; fa++)
#pragma unroll
          for (int fc = 0; fc < 2; fc++)
            pv[fa][fc] = MFMA16(xa[fa][kc], wv[fc], pv[fa][fc], 0, 0, 0);
      }
#pragma unroll
      for (int cb = 0; cb < 2; cb++) {
        float4 bq = *(const float4*)&bt[qbase + 16 * cb + 4 * g];
#pragma unroll
        for (int nb = 0; nb < 4; nb++) {
          int n = 16 * nb + q;
          f32x4 v = pq[cb][nb];
          uint2 w2;
          w2.x = pkbf((v[0] + bq.x) * scl, (v[1] + bq.y) * scl);
          w2.y = pkbf((v[2] + bq.z) * scl, (v[3] + bq.w) * scl);
          *(uint2*)&lds[PW_u + n * 40 + 16 * cb + 4 * g] = w2;
        }
      }
      float bv0 = bt[sbase + q], bv1 = bt[sbase + 16 + q];
#pragma unroll
      for (int fa = 0; fa < 4; fa++)
#pragma unroll
        for (int fc = 0; fc < 2; fc++) {
          int d = 16 * fc + q;
          float bvv = fc ? bv1 : bv0;
          f32x4 v = pv[fa][fc];
          uint2 w2;
          w2.x = pkbf(v[0] + bvv, v[1] + bvv);
          w2.y = pkbf(v[2] + bvv, v[3] + bvv);
          int idx = ((d << 6) + 16 * fa + 4 * g) ^ ((d & 7) << 3);
          *(uint2*)&lds[stage_u + idx] = w2;
        }
    }
    __syncthreads();

    // ================= phase 2a: Lt = K*q^T (both already log2e/sc-scaled)
    f32x4 lt[4][4];
#pragma unroll
    for (int fr = 0; fr < 4; fr++)
#pragma unroll
      for (int fc = 0; fc < 4; fc++) lt[fr][fc] = (f32x4){0.f, 0.f, 0.f, 0.f};
    bf16x8 ka[4], qb[4];
#pragma unroll
    for (int fr = 0; fr < 4; fr++)
      ka[fr] = *(const bf16x8*)&lds[kb_u + (16 * fr + q) * 40 + 8 * g];
#pragma unroll
    for (int fc = 0; fc < 4; fc++)
      qb[fc] = *(const bf16x8*)&lds[PW_u + (16 * fc + q) * 40 + 8 * g];
#pragma unroll
    for (int fr = 0; fr < 4; fr++)
#pragma unroll
      for (int fc = 0; fc < 4; fc++)
        lt[fr][fc] = MFMA16(ka[fr], qb[fc], lt[fr][fc], 0, 0, 0);

    const float4* bfp = ((const float4*)biasF) + (size_t)((wu * 3 + h) * 16) * 64 + lane;
#pragma unroll
    for (int fr = 0; fr < 4; fr++)
#pragma unroll
      for (int fc = 0; fc < 4; fc++) {
        float4 bv = bfp[(fr * 4 + fc) * 64];
        lt[fr][fc][0] += bv.x;
        lt[fr][fc][1] += bv.y;
        lt[fr][fc][2] += bv.z;
        lt[fr][fc][3] += bv.w;
      }

    // softmax over m per column n; P stored UNNORMALIZED (1/s deferred to O)
    float inv4[4];
#pragma unroll
    for (int fc = 0; fc < 4; fc++) {
      float mx = lt[0][fc][0];
#pragma unroll
      for (int fr = 0; fr < 4; fr++)
#pragma unroll
        for (int r = 0; r < 4; r++) mx = fmaxf(mx, lt[fr][fc][r]);
      mx = fmaxf(mx, __shfl_xor(mx, 16));
      mx = fmaxf(mx, __shfl_xor(mx, 32));
      float s = 0.f;
#pragma unroll
      for (int fr = 0; fr < 4; fr++)
#pragma unroll
        for (int r = 0; r < 4; r++) {
          float p = __builtin_exp2f(lt[fr][fc][r] - mx);
          lt[fr][fc][r] = p;
          s += p;
        }
      s += __shfl_xor(s, 16);
      s += __shfl_xor(s, 32);
      inv4[fc] = 1.0f / s;
      int n = 16 * fc + q;
#pragma unroll
      for (int fr = 0; fr < 4; fr++) {
        uint2 w2;
        w2.x = pkbf(lt[fr][fc][0], lt[fr][fc][1]);
        w2.y = pkbf(lt[fr][fc][2], lt[fr][fc][3]);
        int idx = ((n << 6) + 16 * fr + 4 * g) ^ ((n & 7) << 3);
        *(uint2*)&lds[PW_u + idx] = w2;
      }
    }

    // ================= phase 2b: O^T = V^T * P^T  (Ot[d][n])
    f32x4 ot[2][4];
#pragma unroll
    for (int fa = 0; fa < 2; fa++)
#pragma unroll
      for (int fc = 0; fc < 4; fc++) ot[fa][fc] = (f32x4){0.f, 0.f, 0.f, 0.f};
#pragma unroll
    for (int kc = 0; kc < 2; kc++) {
      bf16x8 va[2], pb[4];
#pragma unroll
      for (int fa = 0; fa < 2; fa++) {
        int d = 16 * fa + q;
        va[fa] = *(const bf16x8*)&lds[vb_u + (((d << 6) + 32 * kc + 8 * g) ^ ((d & 7) << 3))];
      }
#pragma unroll
      for (int fc = 0; fc < 4; fc++) {
        int n = 16 * fc + q;
        pb[fc] = *(const bf16x8*)&lds[PW_u + (((n << 6) + 32 * kc + 8 * g) ^ ((n & 7) << 3))];
      }
#pragma unroll
      for (int fa = 0; fa < 2; fa++)
#pragma unroll
        for (int fc = 0; fc < 4; fc++)
          ot[fa][fc] = MFMA16(va[fa], pb[fc], ot[fa][fc], 0, 0, 0);
    }
    // normalize by 1/s (same lane owns column n) and stage O[n][d] at perW offset 0
#pragma unroll
    for (int fa = 0; fa < 2; fa++)
#pragma unroll
      for (int fc = 0; fc < 4; fc++) {
        float iv = inv4[fc];
        int n = 16 * fc + q;
        uint2 w2;
        w2.x = pkbf(ot[fa][fc][0] * iv, ot[fa][fc][1] * iv);
        w2.y = pkbf(ot[fa][fc][2] * iv, ot[fa][fc][3] * iv);
        *(uint2*)&lds[PW_u + n * 40 + 16 * fa + 4 * g] = w2;
      }
    __syncthreads();

    // ================= phase 3: accumulate out/state projections
    bf16x8 ao[4];
#pragma unroll
    for (int tt = 0; tt < 4; tt++)
      ao[tt] = *(const bf16x8*)&lds[9216 + tt * 4096 + (16 * wu + q) * 40 + 8 * g];
    if (h < NH - 1) __syncthreads();  // fence ao reads vs next head's Q staging
#pragma unroll
    for (int fc = 0; fc < 6; fc++) {
      int c = 16 * fc + q;
      bf16x8 b0 = *(const bf16x8*)&WpvB[(size_t)c * 192 + h * 32 + 8 * g];
      bf16x8 b1 = *(const bf16x8*)&WpvB[(size_t)c * 192 + 96 + h * 32 + 8 * g];
      accO[fc] = MFMA16(ao[0], b0, accO[fc], 0, 0, 0);
      accO[fc] = MFMA16(ao[1], b1, accO[fc], 0, 0, 0);
      bf16x8 b2 = *(const bf16x8*)&WphB[(size_t)c * 192 + h * 32 + 8 * g];
      bf16x8 b3 = *(const bf16x8*)&WphB[(size_t)c * 192 + 96 + h * 32 + 8 * g];
      accS[fc] = MFMA16(ao[2], b2, accS[fc], 0, 0, 0);
      accS[fc] = MFMA16(ao[3], b3, accS[fc], 0, 0, 0);
    }
  }

  // ================= epilogue: wave wu owns rows 16*wu..16*wu+15
  float* orow = out + (size_t)b * NSEQ * CDIM;
  float* srow = orow + (size_t)NB * NSEQ * CDIM;
#pragma unroll
  for (int fc = 0; fc < 6; fc++) {
    int c = 16 * fc + q;
    float bo = bpv[c], bh2 = bph[c];
#pragma unroll
    for (int r = 0; r < 4; r++) {
      int n = 16 * wu + 4 * g + r;
      orow[(size_t)n * CDIM + c] = accO[fc][r] + bo;
      srow[(size_t)n * CDIM + c] = accS[fc][r] + bh2;
    }
  }
}

extern "C" void kernel_launch(void* const* d_in, const int* in_sizes, int n_in,
                              void* d_out, int out_size, void* d_ws, size_t ws_size,
                              hipStream_t stream) {
  const float* input_x = (const float*)d_in[0];
  const float* state_x = (const float*)d_in[1];
  const float* Ws   = (const float*)d_in[2];
  const float* bs   = (const float*)d_in[3];
  const float* We   = (const float*)d_in[4];
  const float* be   = (const float*)d_in[5];
  const float* tcv  = (const float*)d_in[6];
  const float* tsv  = (const float*)d_in[7];
  const float* tch  = (const float*)d_in[8];
  const float* tsh  = (const float*)d_in[9];
  const float* Wpv  = (const float*)d_in[10];
  const float* bpv  = (const float*)d_in[11];
  const float* Wph  = (const float*)d_in[12];
  const float* bph  = (const float*)d_in[13];
  const int*   rel  = (const int*)d_in[14];

  float* biasF = (float*)d_ws;                          // 196608 B
  u16* wbf = (u16*)((char*)d_ws + 196608);              // 221184 B bf16 weights

  bias_pre_kernel<<<48, 256, 0, stream>>>(tcv, tsv, tch, tsh, rel, biasF);
  wcvt_kernel<<<432, 256, 0, stream>>>(Ws, We, Wpv, Wph, wbf);
  rwa_kernel<<<NB, 256, 0, stream>>>(input_x, state_x, bs, be, bpv, bph,
                                     biasF, wbf, (float*)d_out);
}

// Round 3
// 713.309 us; speedup vs baseline: 1.4177x; 1.4177x over previous
//
#include <hip/hip_runtime.h>

#define NB 4096
#define NSEQ 64
#define CDIM 96
#define NH 3

typedef __attribute__((ext_vector_type(8))) short bf16x8;
typedef __attribute__((ext_vector_type(4))) float f32x4;
typedef unsigned short u16;

#define MFMA16 __builtin_amdgcn_mfma_f32_16x16x32_bf16
#define LOG2E 1.4426950408889634f

__device__ __forceinline__ unsigned pkbf(float a, float b) {
  unsigned r;
  asm("v_cvt_pk_bf16_f32 %0, %1, %2" : "=v"(r) : "v"(a), "v"(b));
  return r;
}

// ---------------- merged precompute:
// blocks [0,48): bias in MFMA D-frag layout, pre-scaled by log2(e)
//   biasF[(t*3+h)*16 + fr*4+fc][lane] = float4 over r = log2e*tbl_t[rel[n][m],h]
//   m = 16*fr + 4*(lane>>4) + r, n = 16*fc + (lane&15)
// blocks [48,480): weight fp32 -> bf16 (RNE)
//   dst u16: Ws[0..36864) We[..73728) Wpv[..92160) Wph[..110592)
__global__ __launch_bounds__(256) void pre_kernel(
    const float* __restrict__ tcv, const float* __restrict__ tsv,
    const float* __restrict__ tch, const float* __restrict__ tsh,
    const int* __restrict__ rel, float* __restrict__ biasF,
    const float* __restrict__ Ws, const float* __restrict__ We,
    const float* __restrict__ Wpv, const float* __restrict__ Wph,
    u16* __restrict__ dst) {
  int gid = blockIdx.x * 256 + threadIdx.x;
  if (gid < 12288) {
    int idx = gid;
    int t = idx / (3 * 16 * 64);
    int r0 = idx % (3 * 16 * 64);
    int h = r0 / (16 * 64);
    int r1 = r0 % (16 * 64);
    int frag = r1 >> 6;
    int lane = r1 & 63;
    int fr = frag >> 2, fc = frag & 3;
    int g = lane >> 4, q = lane & 15;
    int n = 16 * fc + q;
    int m0 = 16 * fr + 4 * g;
    const float* tbl = (t == 0) ? tcv : (t == 1) ? tsv : (t == 2) ? tch : tsh;
    float4 v;
    v.x = LOG2E * tbl[rel[n * 64 + m0 + 0] * NH + h];
    v.y = LOG2E * tbl[rel[n * 64 + m0 + 1] * NH + h];
    v.z = LOG2E * tbl[rel[n * 64 + m0 + 2] * NH + h];
    v.w = LOG2E * tbl[rel[n * 64 + m0 + 3] * NH + h];
    ((float4*)biasF)[idx] = v;
  } else {
    int i = gid - 12288;
    if (i >= 110592) return;
    float v;
    if (i < 36864) v = Ws[i];
    else if (i < 73728) v = We[i - 36864];
    else if (i < 92160) v = Wpv[i - 73728];
    else v = Wph[i - 92160];
    unsigned u = __builtin_bit_cast(unsigned, v);
    u += 0x7FFFu + ((u >> 16) & 1u);
    dst[i] = (u16)(u >> 16);
  }
}

// ---------------- main fused kernel: one block per window, wave = attn type
// w0: cv (q=qsv(S), K=ks(S), V=vs(S), sc)   w1: sv (qev(E), ke, ve, 1)
// w2: ch (qeh(E), ke, ve, sc)               w3: sh (qsh(S), ks, vs, sc^2)
// Frag conventions (gfx950 16x16x32):
//   A: row=lane&15, k=8*(lane>>4)+j ; B: col=lane&15, k=8*(lane>>4)+j
//   D: col=lane&15, row=4*(lane>>4)+r
// Register-pressure discipline (round-2 spill post-mortem):
//   - launch_bounds min 2 (NOT 3): allocator must never be forced to spill
//   - xa scoped per-head (dead during phase-2's lt[4][4] peak)
//   - phase-1 q-pass and K/V-pass sequential (32 concurrent acc, not 64)
__global__ __launch_bounds__(256, 2) void rwa_kernel(
    const float* __restrict__ Xin, const float* __restrict__ Xst,
    const float* __restrict__ bs, const float* __restrict__ be,
    const float* __restrict__ bpv, const float* __restrict__ bph,
    const float* __restrict__ biasF, const u16* __restrict__ wbf,
    float* __restrict__ out) {
  const int b = blockIdx.x;
  const int t = threadIdx.x;
  const int wu = __builtin_amdgcn_readfirstlane(t >> 6);
  const int lane = t & 63;
  const int g = lane >> 4;
  const int q = lane & 15;

  // LDS map (u16 units), 25600 u16 = 51200 B -> 3 blocks/CU if regs allow:
  // KS[64][40]=0  KE=2560  VSt swz[32][64]=5120  VEt=7168
  // perW[w]=9216+w*4096: Q[64][40] / P swz[64][64] / O[64][40] (overlaid)
  __shared__ __align__(16) u16 lds[25600];

  const int KS_u = 0, KE_u = 2560, VST_u = 5120, VET_u = 7168;
  const int PW_u = 9216 + wu * 4096;

  const float SC = 0.17677669529663687f;  // 32^-0.5
  const bool isS = (wu == 0 || wu == 3);
  const float* X = isS ? Xst : Xin;
  const u16* Wt = isS ? wbf : (wbf + 36864);
  const float* bt = isS ? bs : be;
  const int qf = (wu < 2) ? 2 : 3;
  const int sf = (wu < 2) ? 0 : 1;
  const int kb_u = (wu == 1 || wu == 2) ? KE_u : KS_u;
  const int vb_u = (wu == 1 || wu == 2) ? VET_u : VST_u;
  const int stage_u = (wu == 0) ? KS_u : (wu == 1) ? KE_u : (wu == 2) ? VET_u : VST_u;
  // q staged pre-scaled by sc*log2e; bias pre-scaled by log2e -> raw exp2
  const float scl = ((wu == 0 || wu == 2) ? SC : ((wu == 1) ? 1.0f : SC * SC)) * LOG2E;

  const u16* WpvB = wbf + 73728;
  const u16* WphB = wbf + 92160;

  // ---- final-projection accumulators: rows n=16*wu+4g+r, cols c=16*fc+q
  f32x4 accO[6], accS[6];
#pragma unroll
  for (int i = 0; i < 6; i++) {
    accO[i] = (f32x4){0.f, 0.f, 0.f, 0.f};
    accS[i] = (f32x4){0.f, 0.f, 0.f, 0.f};
  }

#pragma unroll 1
  for (int h = 0; h < NH; h++) {
    const int qbase = qf * CDIM + h * 32;
    const int sbase = sf * CDIM + h * 32;

    // ---- X fragments for THIS head only (laundered base defeats LICM so the
    // 48 regs are not live across phases 2/3)
    const float* Xp = X + ((size_t)b * NSEQ + q) * CDIM;
    asm volatile("" : "+v"(Xp));
    bf16x8 xa[4][3];
#pragma unroll
    for (int fa = 0; fa < 4; fa++) {
      const float* xrow = Xp + fa * 16 * CDIM;
#pragma unroll
      for (int kc = 0; kc < 3; kc++) {
        float4 lo = *(const float4*)(xrow + 32 * kc + 8 * g);
        float4 hi = *(const float4*)(xrow + 32 * kc + 8 * g + 4);
        union { bf16x8 v; unsigned u[4]; } tmp;
        tmp.u[0] = pkbf(lo.x, lo.y);
        tmp.u[1] = pkbf(lo.z, lo.w);
        tmp.u[2] = pkbf(hi.x, hi.y);
        tmp.u[3] = pkbf(hi.z, hi.w);
        xa[fa][kc] = tmp.v;
      }
    }

    // ================= phase 1a: q projection, swapped: D[d][n], d=16cb+4g+r, n=16nb+q
    {
      f32x4 pq[2][4];
#pragma unroll
      for (int cb = 0; cb < 2; cb++)
#pragma unroll
        for (int nb = 0; nb < 4; nb++) pq[cb][nb] = (f32x4){0.f, 0.f, 0.f, 0.f};
#pragma unroll
      for (int kc = 0; kc < 3; kc++) {
        bf16x8 wq[2];
#pragma unroll
        for (int cb = 0; cb < 2; cb++)
          wq[cb] = *(const bf16x8*)&Wt[(size_t)(qbase + 16 * cb + q) * CDIM + 32 * kc + 8 * g];
#pragma unroll
        for (int cb = 0; cb < 2; cb++)
#pragma unroll
          for (int nb = 0; nb < 4; nb++)
            pq[cb][nb] = MFMA16(wq[cb], xa[nb][kc], pq[cb][nb], 0, 0, 0);
      }
#pragma unroll
      for (int cb = 0; cb < 2; cb++) {
        float4 bq = *(const float4*)&bt[qbase + 16 * cb + 4 * g];
#pragma unroll
        for (int nb = 0; nb < 4; nb++) {
          int n = 16 * nb + q;
          f32x4 v = pq[cb][nb];
          uint2 w2;
          w2.x = pkbf((v[0] + bq.x) * scl, (v[1] + bq.y) * scl);
          w2.y = pkbf((v[2] + bq.z) * scl, (v[3] + bq.w) * scl);
          *(uint2*)&lds[PW_u + n * 40 + 16 * cb + 4 * g] = w2;
        }
      }
    }

    // ================= phase 1b: shared slice (K swapped / V original + swizzle)
    if (wu < 2) {
      f32x4 pk2[2][4];
#pragma unroll
      for (int cb = 0; cb < 2; cb++)
#pragma unroll
        for (int nb = 0; nb < 4; nb++) pk2[cb][nb] = (f32x4){0.f, 0.f, 0.f, 0.f};
#pragma unroll
      for (int kc = 0; kc < 3; kc++) {
        bf16x8 wk[2];
#pragma unroll
        for (int cb = 0; cb < 2; cb++)
          wk[cb] = *(const bf16x8*)&Wt[(size_t)(sbase + 16 * cb + q) * CDIM + 32 * kc + 8 * g];
#pragma unroll
        for (int cb = 0; cb < 2; cb++)
#pragma unroll
          for (int nb = 0; nb < 4; nb++)
            pk2[cb][nb] = MFMA16(wk[cb], xa[nb][kc], pk2[cb][nb], 0, 0, 0);
      }
#pragma unroll
      for (int cb = 0; cb < 2; cb++) {
        float4 bk = *(const float4*)&bt[sbase + 16 * cb + 4 * g];
#pragma unroll
        for (int nb = 0; nb < 4; nb++) {
          int n = 16 * nb + q;
          f32x4 u = pk2[cb][nb];
          uint2 k2;
          k2.x = pkbf(u[0] + bk.x, u[1] + bk.y);
          k2.y = pkbf(u[2] + bk.z, u[3] + bk.w);
          *(uint2*)&lds[stage_u + n * 40 + 16 * cb + 4 * g] = k2;
        }
      }
    } else {
      f32x4 pv[4][2];
#pragma unroll
      for (int fa = 0; fa < 4; fa++)
#pragma unroll
        for (int fc = 0; fc < 2; fc++) pv[fa][fc] = (f32x4){0.f, 0.f, 0.f, 0.f};
#pragma unroll
      for (int kc = 0; kc < 3; kc++) {
        bf16x8 wv[2];
#pragma unroll
        for (int fc = 0; fc < 2; fc++)
          wv[fc] = *(const bf16x8*)&Wt[(size_t)(sbase + 16 * fc + q) * CDIM + 32 * kc + 8 * g];
#pragma unroll
        for (int fa = 0; fa < 4; fa++)
#pragma unroll
          for (int fc = 0; fc < 2; fc++)
            pv[fa][fc] = MFMA16(xa[fa][kc], wv[fc], pv[fa][fc], 0, 0, 0);
      }
      float bv0 = bt[sbase + q], bv1 = bt[sbase + 16 + q];
#pragma unroll
      for (int fa = 0; fa < 4; fa++)
#pragma unroll
        for (int fc = 0; fc < 2; fc++) {
          int d = 16 * fc + q;
          float bvv = fc ? bv1 : bv0;
          f32x4 v = pv[fa][fc];
          uint2 w2;
          w2.x = pkbf(v[0] + bvv, v[1] + bvv);
          w2.y = pkbf(v[2] + bvv, v[3] + bvv);
          int idx = ((d << 6) + 16 * fa + 4 * g) ^ ((d & 7) << 3);
          *(uint2*)&lds[stage_u + idx] = w2;
        }
    }
    __syncthreads();

    // ================= phase 2a: Lt = K*q^T, C initialized from bias frags
    f32x4 lt[4][4];
    const float4* bfp = ((const float4*)biasF) + (size_t)((wu * 3 + h) * 16) * 64 + lane;
#pragma unroll
    for (int fr = 0; fr < 4; fr++)
#pragma unroll
      for (int fc = 0; fc < 4; fc++) {
        float4 bv = bfp[(fr * 4 + fc) * 64];
        lt[fr][fc] = (f32x4){bv.x, bv.y, bv.z, bv.w};
      }
    bf16x8 ka[4], qb[4];
#pragma unroll
    for (int fr = 0; fr < 4; fr++)
      ka[fr] = *(const bf16x8*)&lds[kb_u + (16 * fr + q) * 40 + 8 * g];
#pragma unroll
    for (int fc = 0; fc < 4; fc++)
      qb[fc] = *(const bf16x8*)&lds[PW_u + (16 * fc + q) * 40 + 8 * g];
#pragma unroll
    for (int fr = 0; fr < 4; fr++)
#pragma unroll
      for (int fc = 0; fc < 4; fc++)
        lt[fr][fc] = MFMA16(ka[fr], qb[fc], lt[fr][fc], 0, 0, 0);

    // softmax over m per column n; P stored UNNORMALIZED (1/s deferred to O)
    float inv4[4];
#pragma unroll
    for (int fc = 0; fc < 4; fc++) {
      float mx = lt[0][fc][0];
#pragma unroll
      for (int fr = 0; fr < 4; fr++)
#pragma unroll
        for (int r = 0; r < 4; r++) mx = fmaxf(mx, lt[fr][fc][r]);
      mx = fmaxf(mx, __shfl_xor(mx, 16));
      mx = fmaxf(mx, __shfl_xor(mx, 32));
      float s = 0.f;
#pragma unroll
      for (int fr = 0; fr < 4; fr++)
#pragma unroll
        for (int r = 0; r < 4; r++) {
          float p = __builtin_exp2f(lt[fr][fc][r] - mx);
          lt[fr][fc][r] = p;
          s += p;
        }
      s += __shfl_xor(s, 16);
      s += __shfl_xor(s, 32);
      inv4[fc] = 1.0f / s;
      int n = 16 * fc + q;
#pragma unroll
      for (int fr = 0; fr < 4; fr++) {
        uint2 w2;
        w2.x = pkbf(lt[fr][fc][0], lt[fr][fc][1]);
        w2.y = pkbf(lt[fr][fc][2], lt[fr][fc][3]);
        int idx = ((n << 6) + 16 * fr + 4 * g) ^ ((n & 7) << 3);
        *(uint2*)&lds[PW_u + idx] = w2;
      }
    }

    // ================= phase 2b: O^T = V^T * P^T  (Ot[d][n])
    f32x4 ot[2][4];
#pragma unroll
    for (int fa = 0; fa < 2; fa++)
#pragma unroll
      for (int fc = 0; fc < 4; fc++) ot[fa][fc] = (f32x4){0.f, 0.f, 0.f, 0.f};
#pragma unroll
    for (int kc = 0; kc < 2; kc++) {
      bf16x8 va[2], pb[4];
#pragma unroll
      for (int fa = 0; fa < 2; fa++) {
        int d = 16 * fa + q;
        va[fa] = *(const bf16x8*)&lds[vb_u + (((d << 6) + 32 * kc + 8 * g) ^ ((d & 7) << 3))];
      }
#pragma unroll
      for (int fc = 0; fc < 4; fc++) {
        int n = 16 * fc + q;
        pb[fc] = *(const bf16x8*)&lds[PW_u + (((n << 6) + 32 * kc + 8 * g) ^ ((n & 7) << 3))];
      }
#pragma unroll
      for (int fa = 0; fa < 2; fa++)
#pragma unroll
        for (int fc = 0; fc < 4; fc++)
          ot[fa][fc] = MFMA16(va[fa], pb[fc], ot[fa][fc], 0, 0, 0);
    }
    // normalize by 1/s (same lane owns column n) and stage O[n][d] at perW offset 0
#pragma unroll
    for (int fa = 0; fa < 2; fa++)
#pragma unroll
      for (int fc = 0; fc < 4; fc++) {
        float iv = inv4[fc];
        int n = 16 * fc + q;
        uint2 w2;
        w2.x = pkbf(ot[fa][fc][0] * iv, ot[fa][fc][1] * iv);
        w2.y = pkbf(ot[fa][fc][2] * iv, ot[fa][fc][3] * iv);
        *(uint2*)&lds[PW_u + n * 40 + 16 * fa + 4 * g] = w2;
      }
    __syncthreads();

    // ================= phase 3: accumulate out/state projections
    bf16x8 ao[4];
#pragma unroll
    for (int tt = 0; tt < 4; tt++)
      ao[tt] = *(const bf16x8*)&lds[9216 + tt * 4096 + (16 * wu + q) * 40 + 8 * g];
    if (h < NH - 1) __syncthreads();  // fence ao reads vs next head's Q staging
#pragma unroll
    for (int fc = 0; fc < 6; fc++) {
      int c = 16 * fc + q;
      bf16x8 b0 = *(const bf16x8*)&WpvB[(size_t)c * 192 + h * 32 + 8 * g];
      bf16x8 b1 = *(const bf16x8*)&WpvB[(size_t)c * 192 + 96 + h * 32 + 8 * g];
      accO[fc] = MFMA16(ao[0], b0, accO[fc], 0, 0, 0);
      accO[fc] = MFMA16(ao[1], b1, accO[fc], 0, 0, 0);
      bf16x8 b2 = *(const bf16x8*)&WphB[(size_t)c * 192 + h * 32 + 8 * g];
      bf16x8 b3 = *(const bf16x8*)&WphB[(size_t)c * 192 + 96 + h * 32 + 8 * g];
      accS[fc] = MFMA16(ao[2], b2, accS[fc], 0, 0, 0);
      accS[fc] = MFMA16(ao[3], b3, accS[fc], 0, 0, 0);
    }
  }

  // ================= epilogue: wave wu owns rows 16*wu..16*wu+15
  float* orow = out + (size_t)b * NSEQ * CDIM;
  float* srow = orow + (size_t)NB * NSEQ * CDIM;
#pragma unroll
  for (int fc = 0; fc < 6; fc++) {
    int c = 16 * fc + q;
    float bo = bpv[c], bh2 = bph[c];
#pragma unroll
    for (int r = 0; r < 4; r++) {
      int n = 16 * wu + 4 * g + r;
      orow[(size_t)n * CDIM + c] = accO[fc][r] + bo;
      srow[(size_t)n * CDIM + c] = accS[fc][r] + bh2;
    }
  }
}

extern "C" void kernel_launch(void* const* d_in, const int* in_sizes, int n_in,
                              void* d_out, int out_size, void* d_ws, size_t ws_size,
                              hipStream_t stream) {
  const float* input_x = (const float*)d_in[0];
  const float* state_x = (const float*)d_in[1];
  const float* Ws   = (const float*)d_in[2];
  const float* bs   = (const float*)d_in[3];
  const float* We   = (const float*)d_in[4];
  const float* be   = (const float*)d_in[5];
  const float* tcv  = (const float*)d_in[6];
  const float* tsv  = (const float*)d_in[7];
  const float* tch  = (const float*)d_in[8];
  const float* tsh  = (const float*)d_in[9];
  const float* Wpv  = (const float*)d_in[10];
  const float* bpv  = (const float*)d_in[11];
  const float* Wph  = (const float*)d_in[12];
  const float* bph  = (const float*)d_in[13];
  const int*   rel  = (const int*)d_in[14];

  float* biasF = (float*)d_ws;                          // 196608 B
  u16* wbf = (u16*)((char*)d_ws + 196608);              // 221184 B bf16 weights

  pre_kernel<<<480, 256, 0, stream>>>(tcv, tsv, tch, tsh, rel, biasF,
                                      Ws, We, Wpv, Wph, wbf);
  rwa_kernel<<<NB, 256, 0, stream>>>(input_x, state_x, bs, be, bpv, bph,
                                     biasF, wbf, (float*)d_out);
}